// Round 1
// baseline (236.771 us; speedup 1.0000x reference)
//
#include <hip/hip_runtime.h>

#define B_ 8
#define N_ 512
#define D_ 256
#define H_ 8
#define HD_ 32
#define E_ 8192
#define EA_ 32

// log(1e-6)
#define LOG1EM6 -13.815510557964274f
// 1/sqrt(32)
#define SCALE 0.17677669529663687f

// ---------------------------------------------------------------------------
// Kernel 1: QKV projection GEMM.  x:(B*N,256) @ W:(256,768) + b
// Output scattered into qkv[3][B][H][N][HD] so K/V panels are contiguous.
// 128x128 tile, 256 threads, 8x8 per thread, K-chunk 16.
// ---------------------------------------------------------------------------
__global__ __launch_bounds__(256, 1) void qkv_gemm(
    const float* __restrict__ x, const float* __restrict__ W,
    const float* __restrict__ bias, float* __restrict__ qkv)
{
    __shared__ float As[16][128];
    __shared__ float Bs[16][128];
    const int tid = threadIdx.x;
    const int m0 = blockIdx.y * 128;
    const int n0 = blockIdx.x * 128;
    const int tx = tid & 15, ty = tid >> 4;

    float acc[8][8];
#pragma unroll
    for (int i = 0; i < 8; i++)
#pragma unroll
        for (int j = 0; j < 8; j++) acc[i][j] = 0.0f;

    for (int kc = 0; kc < 256; kc += 16) {
#pragma unroll
        for (int it = 0; it < 2; it++) {
            int i4 = tid + it * 256;          // 0..511
            int r  = i4 >> 2;                 // 0..127
            int c4 = i4 & 3;                  // k-quad
            float4 v = *(const float4*)&x[(m0 + r) * 256 + kc + c4 * 4];
            As[c4 * 4 + 0][r] = v.x;
            As[c4 * 4 + 1][r] = v.y;
            As[c4 * 4 + 2][r] = v.z;
            As[c4 * 4 + 3][r] = v.w;
        }
#pragma unroll
        for (int it = 0; it < 2; it++) {
            int i4 = tid + it * 256;
            int kr = i4 >> 5;                 // 0..15
            int c4 = i4 & 31;                 // 0..31
            *(float4*)&Bs[kr][c4 * 4] =
                *(const float4*)&W[(kc + kr) * 768 + n0 + c4 * 4];
        }
        __syncthreads();
#pragma unroll
        for (int k = 0; k < 16; k++) {
            float a[8], bb[8];
            *(float4*)&a[0]  = *(float4*)&As[k][ty * 8];
            *(float4*)&a[4]  = *(float4*)&As[k][ty * 8 + 4];
            *(float4*)&bb[0] = *(float4*)&Bs[k][tx * 8];
            *(float4*)&bb[4] = *(float4*)&Bs[k][tx * 8 + 4];
#pragma unroll
            for (int i = 0; i < 8; i++)
#pragma unroll
                for (int j = 0; j < 8; j++) acc[i][j] += a[i] * bb[j];
        }
        __syncthreads();
    }

    // epilogue: col -> (which, h, hd0); row -> (b, n)
    const int col0  = n0 + tx * 8;
    const int which = col0 >> 8;
    const int h     = (col0 >> 5) & 7;
    const int hd0   = col0 & 31;              // multiple of 8
#pragma unroll
    for (int i = 0; i < 8; i++) {
        int row = m0 + ty * 8 + i;
        int b = row >> 9, n = row & 511;
        float* dst = qkv + (((size_t)(which * B_ + b) * H_ + h) * N_ + n) * HD_ + hd0;
#pragma unroll
        for (int j = 0; j < 8; j++) dst[j] = acc[i][j] + bias[col0 + j];
    }
}

// ---------------------------------------------------------------------------
// Kernel 2: per-edge modified focus log + scatter-winner selection.
// mlog[b][h][e] = max(-(d-ms)^2/(2*mw^2+1e-6), log(1e-6))
// sel[b][u][v]  = max edge id targeting (u,v)   (numpy last-write-wins)
// ---------------------------------------------------------------------------
__global__ __launch_bounds__(256) void edge_kernel(
    const float* __restrict__ edge_attr, const int* __restrict__ edge_index,
    const float* __restrict__ adj,
    const float* __restrict__ ds_W, const float* __restrict__ ds_b,
    const float* __restrict__ dw_W, const float* __restrict__ dw_b,
    const float* __restrict__ shifts, const float* __restrict__ widths,
    float* __restrict__ mlog, int* __restrict__ sel)
{
    __shared__ float ea[256 * 33];
    __shared__ float dsW[256], dwW[256];
    const int tid = threadIdx.x;
    const int b   = blockIdx.x >> 5;
    const int e0  = (blockIdx.x & 31) * 256;

    const float* eabase = edge_attr + ((size_t)b * E_ + e0) * EA_;
#pragma unroll
    for (int it = 0; it < 32; it++) {
        int i = tid + it * 256;
        ea[(i >> 5) * 33 + (i & 31)] = eabase[i];
    }
    dsW[tid] = ds_W[tid];
    dwW[tid] = dw_W[tid];
    __syncthreads();

    const int e  = e0 + tid;
    const int eu = edge_index[(size_t)b * 2 * E_ + e];
    const int ev = edge_index[(size_t)b * 2 * E_ + E_ + e];
    const float d = adj[((size_t)b * N_ + eu) * N_ + ev];

    float ds[8], dw[8];
#pragma unroll
    for (int h = 0; h < 8; h++) { ds[h] = ds_b[h]; dw[h] = dw_b[h]; }
#pragma unroll
    for (int k = 0; k < 32; k++) {
        float a = ea[tid * 33 + k];
#pragma unroll
        for (int h = 0; h < 8; h++) {
            ds[h] += a * dsW[k * 8 + h];
            dw[h] += a * dwW[k * 8 + h];
        }
    }
#pragma unroll
    for (int h = 0; h < 8; h++) {
        float ms = shifts[h] + ds[h];
        float mw = widths[h] + dw[h];
        float t  = d - ms;
        float ml = fmaxf(-(t * t) / (2.0f * mw * mw + 1e-6f), LOG1EM6);
        mlog[((size_t)(b * H_ + h)) * E_ + e] = ml;
    }
    atomicMax(&sel[((size_t)b * N_ + eu) * N_ + ev], e);
}

// ---------------------------------------------------------------------------
// lane reduction helper: fold 2*CNT partials across lane-pairs at XOR=MASK
// ---------------------------------------------------------------------------
template <int CNT, int MASK>
__device__ __forceinline__ void red_stage(float* part, int lane)
{
    const bool up = (lane & MASK) != 0;
#pragma unroll
    for (int k = 0; k < CNT; k++) {
        float send = up ? part[k] : part[k + CNT];
        float recv = __shfl_xor(send, MASK, 64);
        part[k] = (up ? part[k + CNT] : part[k]) + recv;
    }
}

// ---------------------------------------------------------------------------
// Kernel 3: fused scores + focus/override/self-loop + softmax + PV.
// One block per (b, h, 64-row tile). K,V staged in LDS (stride 36 floats).
// 4 waves, each wave 16 rows in groups of 4.
// ---------------------------------------------------------------------------
__global__ __launch_bounds__(256, 1) void attn_kernel(
    const float* __restrict__ qkv, const float* __restrict__ adj,
    const float* __restrict__ mlog, const int* __restrict__ sel,
    const float* __restrict__ shifts, const float* __restrict__ widths,
    const float* __restrict__ slw_arr, float* __restrict__ out)
{
    extern __shared__ float smem[];
    float* K_lds = smem;                    // 512*36
    float* V_lds = smem + 512 * 36;         // 512*36
    float* Q_lds = smem + 2 * 512 * 36;     // 64*32

    const int tid = threadIdx.x;
    const int bid = blockIdx.x;             // b*64 + h*8 + rt
    const int b  = bid >> 6;
    const int h  = (bid >> 3) & 7;
    const int rt = bid & 7;
    const int u0 = rt * 64;

    const float* Kg = qkv + ((size_t)(1 * B_ + b) * H_ + h) * N_ * HD_;
    const float* Vg = qkv + ((size_t)(2 * B_ + b) * H_ + h) * N_ * HD_;
    const float* Qg = qkv + ((size_t)(0 * B_ + b) * H_ + h) * N_ * HD_ + u0 * HD_;

#pragma unroll
    for (int it = 0; it < 16; it++) {
        int i4 = tid + it * 256;            // 0..4095
        int v  = i4 >> 3;
        int d4 = i4 & 7;
        *(float4*)&K_lds[v * 36 + d4 * 4] = ((const float4*)Kg)[i4];
        *(float4*)&V_lds[v * 36 + d4 * 4] = ((const float4*)Vg)[i4];
    }
#pragma unroll
    for (int it = 0; it < 2; it++) {
        int i4 = tid + it * 256;
        ((float4*)Q_lds)[i4] = ((const float4*)Qg)[i4];
    }
    __syncthreads();

    const float s_h   = shifts[h];
    const float w_h   = widths[h];
    const float inv2w = 1.0f / (2.0f * w_h * w_h + 1e-6f);
    const float slw   = slw_arr[h];

    const int wv   = tid >> 6;
    const int lane = tid & 63;
    const float* mlg = mlog + ((size_t)(b * H_ + h)) * E_;

    for (int g = 0; g < 4; g++) {
        const int ul0 = wv * 16 + g * 4;    // local row base (0..60)

        // prefetch adj + sel for the 4 rows (hides global latency under QK)
        float adjv[4][8];
        int   selv[4][8];
#pragma unroll
        for (int r = 0; r < 4; r++) {
            const int u = u0 + ul0 + r;
            const float* arow = adj + ((size_t)b * N_ + u) * N_;
            const int*   srow = sel + ((size_t)b * N_ + u) * N_;
#pragma unroll
            for (int j = 0; j < 8; j++) {
                adjv[r][j] = arow[lane + 64 * j];
                selv[r][j] = srow[lane + 64 * j];
            }
        }

        // QK^T for 4 rows x 512 cols
        float acc[4][8];
#pragma unroll
        for (int r = 0; r < 4; r++)
#pragma unroll
            for (int j = 0; j < 8; j++) acc[r][j] = 0.0f;

#pragma unroll
        for (int d4 = 0; d4 < 8; d4++) {
            float4 k4[8];
#pragma unroll
            for (int j = 0; j < 8; j++)
                k4[j] = *(float4*)&K_lds[(lane + 64 * j) * 36 + d4 * 4];
#pragma unroll
            for (int r = 0; r < 4; r++) {
                float4 q4 = *(float4*)&Q_lds[(ul0 + r) * 32 + d4 * 4];
#pragma unroll
                for (int j = 0; j < 8; j++)
                    acc[r][j] += q4.x * k4[j].x + q4.y * k4[j].y +
                                 q4.z * k4[j].z + q4.w * k4[j].w;
            }
        }

        // per-row adjust + softmax + PV
#pragma unroll
        for (int r = 0; r < 4; r++) {
            const int u = u0 + ul0 + r;
            float af[8];
#pragma unroll
            for (int j = 0; j < 8; j++) {
                float a = acc[r][j] * SCALE;
                int   sv = selv[r][j];
                float ov;
                if (sv >= 0) {
                    ov = mlg[sv];           // edge override (replaces baseline)
                } else {
                    float t = adjv[r][j] - s_h;
                    ov = fmaxf(-(t * t) * inv2w, LOG1EM6);
                }
                a += ov;
                if (lane + 64 * j == u) a += slw;   // self-loop
                af[j] = a;
            }
            // row max
            float m = af[0];
#pragma unroll
            for (int j = 1; j < 8; j++) m = fmaxf(m, af[j]);
#pragma unroll
            for (int mk = 32; mk >= 1; mk >>= 1)
                m = fmaxf(m, __shfl_xor(m, mk, 64));
            // exp + sum
            float p[8];
            float ssum = 0.0f;
#pragma unroll
            for (int j = 0; j < 8; j++) {
                p[j] = __expf(af[j] - m);
                ssum += p[j];
            }
#pragma unroll
            for (int mk = 32; mk >= 1; mk >>= 1)
                ssum += __shfl_xor(ssum, mk, 64);
            const float pinv = 1.0f / ssum;
#pragma unroll
            for (int j = 0; j < 8; j++) p[j] *= pinv;

            // PV: partial out dims in registers
            float part[32];
#pragma unroll
            for (int d = 0; d < 32; d++) part[d] = 0.0f;
#pragma unroll
            for (int d4 = 0; d4 < 8; d4++) {
#pragma unroll
                for (int j = 0; j < 8; j++) {
                    float4 v4 = *(float4*)&V_lds[(lane + 64 * j) * 36 + d4 * 4];
                    part[d4 * 4 + 0] += p[j] * v4.x;
                    part[d4 * 4 + 1] += p[j] * v4.y;
                    part[d4 * 4 + 2] += p[j] * v4.z;
                    part[d4 * 4 + 3] += p[j] * v4.w;
                }
            }
            // reduce 32 dims across 64 lanes; lane pair (2d,2d+1) owns dim d
            red_stage<16, 32>(part, lane);
            red_stage<8, 16>(part, lane);
            red_stage<4, 8>(part, lane);
            red_stage<2, 4>(part, lane);
            red_stage<1, 2>(part, lane);
            float tot = part[0] + __shfl_xor(part[0], 1, 64);
            if (!(lane & 1)) {
                int dd = lane >> 1;
                out[((size_t)b * N_ + u) * D_ + h * HD_ + dd] = tot;
            }
        }
    }
}

// ---------------------------------------------------------------------------
extern "C" void kernel_launch(void* const* d_in, const int* in_sizes, int n_in,
                              void* d_out, int out_size, void* d_ws, size_t ws_size,
                              hipStream_t stream)
{
    const float* x          = (const float*)d_in[0];
    const float* adj        = (const float*)d_in[1];
    const int*   edge_index = (const int*)d_in[2];
    const float* edge_attr  = (const float*)d_in[3];
    const float* qkv_W      = (const float*)d_in[6];
    const float* qkv_b      = (const float*)d_in[7];
    const float* ds_W       = (const float*)d_in[12];
    const float* ds_b       = (const float*)d_in[13];
    const float* dw_W       = (const float*)d_in[14];
    const float* dw_b       = (const float*)d_in[15];
    const float* shifts     = (const float*)d_in[16];
    const float* widths     = (const float*)d_in[17];
    const float* slw        = (const float*)d_in[18];
    float* out = (float*)d_out;

    float* qkv  = (float*)d_ws;                              // 3*B*H*N*HD f32
    float* mlog = qkv + (size_t)3 * B_ * H_ * N_ * HD_;      // B*H*E f32
    int*   sel  = (int*)(mlog + (size_t)B_ * H_ * E_);       // B*N*N i32

    hipMemsetAsync(sel, 0xFF, (size_t)B_ * N_ * N_ * sizeof(int), stream);

    qkv_gemm<<<dim3(6, 32), 256, 0, stream>>>(x, qkv_W, qkv_b, qkv);

    edge_kernel<<<dim3(256), 256, 0, stream>>>(edge_attr, edge_index, adj,
                                               ds_W, ds_b, dw_W, dw_b,
                                               shifts, widths, mlog, sel);

    hipFuncSetAttribute((const void*)attn_kernel,
                        hipFuncAttributeMaxDynamicSharedMemorySize, 155648);
    attn_kernel<<<dim3(512), 256, 155648, stream>>>(qkv, adj, mlog, sel,
                                                    shifts, widths, slw, out);
}